// Round 8
// baseline (90.192 us; speedup 1.0000x reference)
//
#include <hip/hip_runtime.h>

// ---------------------------------------------------------------------------
// MalConvLowMem as GEMM: M=15748 windows (4096 contiguous floats), N=256
// (w1|w2), K=4096; epilogue g=(c1+b1)*sigmoid(c2+b2), max over positions.
// R8 = R7 + HALVED BARRIERS: ring-4 A in LDS, one lgkmcnt(0)+s_barrier per
// 2 K-steps (superstep). Per superstep: compute slots ks,ks+1; stage ks+2,
// ks+3 (data loaded 2 supersteps ago); issue A loads for ks+4,ks+5 and B for
// ks+1,ks+2. B in registers, fragment-major, per-wave-private 32-col slices.
// BM=32, BN=256, 512 thr / 8 waves, wave tile 32x32 (acc[2][2]).
// ---------------------------------------------------------------------------

#define T_LEN 2000000
#define P_CNT 3937
#define M_TOT 15748
#define KD    4096

typedef __attribute__((ext_vector_type(8))) short short8;
typedef __attribute__((ext_vector_type(4))) float f32x4;

static __device__ __forceinline__ unsigned short f2bf(float f) {
    unsigned u = __builtin_bit_cast(unsigned, f);
    unsigned r = (u + 0x7FFFu + ((u >> 16) & 1u)) >> 16;   // RNE
    return (unsigned short)r;
}

static __device__ __forceinline__ unsigned ordenc(float f) {
    unsigned u = __builtin_bit_cast(unsigned, f);
    return (u & 0x80000000u) ? ~u : (u | 0x80000000u);
}

// row m (clamped) -> flat float offset of window start in x
static __device__ __forceinline__ size_t row_base(int m) {
    if (m > M_TOT - 1) m = M_TOT - 1;
    int bb = m / P_CNT;
    int p  = m - bb * P_CNT;
    int j, kp;
    if (p < 3875) { j = p / 125; kp = p - j * 125; }
    else          { j = 31;      kp = p - 3875; }
    long pos = (long)j * 63489 + (long)kp * 512;
    return ((size_t)bb * T_LEN + (size_t)pos) * 8u;
}

// 4 fp32 -> 4 bf16 (uint2) via v_cvt_pk_bf16_f32 (RNE)
static __device__ __forceinline__ uint2 cvt4(float4 v) {
    unsigned lo, hi;
    asm("v_cvt_pk_bf16_f32 %0, %1, %2" : "=v"(lo) : "v"(v.x), "v"(v.y));
    asm("v_cvt_pk_bf16_f32 %0, %1, %2" : "=v"(hi) : "v"(v.z), "v"(v.w));
    uint2 u; u.x = lo; u.y = hi;
    return u;
}

// ---------------------------------------------------------------------------
// Kernel 1: repack weights FRAGMENT-MAJOR (proven R6/R7):
// 16B chunk c = ((ks*2+kq)*16+nt)*64+l holds W'[n=nt*16+(l&15)]
// [k=ks*64+kq*32+(l>>4)*8+0..7] bf16, W'[n][k]=(n<128?w1:w2)[n&127][k&7][k>>3].
// ---------------------------------------------------------------------------
__global__ __launch_bounds__(256) void pack_w(const float* __restrict__ w1,
                                              const float* __restrict__ w2,
                                              uint4* __restrict__ Bpf,
                                              unsigned* __restrict__ outu) {
    int c = blockIdx.x * 256 + threadIdx.x;         // grid 512 -> 131072
    if (c < 512) outu[c] = 0u;
    if (c >= 131072) return;
    int l  = c & 63;
    int nt = (c >> 6) & 15;
    int kq = (c >> 10) & 1;
    int ks = c >> 11;
    int n  = nt * 16 + (l & 15);
    int kb = ks * 64 + kq * 32 + ((l >> 4) << 3);
    const float* src = (n < 128) ? w1 : w2;
    int cc = n & 127;
    unsigned short h[8];
#pragma unroll
    for (int j = 0; j < 8; ++j) {
        int k = kb + j;
        h[j] = f2bf(src[cc * 4096 + (k & 7) * 512 + (k >> 3)]);
    }
    uint4 v;
    v.x = (unsigned)h[0] | ((unsigned)h[1] << 16);
    v.y = (unsigned)h[2] | ((unsigned)h[3] << 16);
    v.z = (unsigned)h[4] | ((unsigned)h[5] << 16);
    v.w = (unsigned)h[6] | ((unsigned)h[7] << 16);
    Bpf[c] = v;
}

// ---------------------------------------------------------------------------
// Kernel 2: GEMM + gate + max.
// ---------------------------------------------------------------------------
#define LOAD_B(BB, KS)                                                         \
    do {                                                                       \
        _Pragma("unroll")                                                      \
        for (int kq = 0; kq < 2; ++kq)                                         \
            _Pragma("unroll")                                                  \
            for (int nf = 0; nf < 2; ++nf)                                     \
                BB[kq][nf] = Bq[((KS) * 2 + kq) * 1024 + bbase + nf * 64];     \
    } while (0)

#define HALF(KS, BC)                                                           \
    do {                                                                       \
        const char* As = smem + ((KS) & 3) * 4096;                             \
        _Pragma("unroll")                                                      \
        for (int kq = 0; kq < 2; ++kq) {                                       \
            short8 af0 = *(const short8*)(As + aro[kq][0]);                    \
            short8 af1 = *(const short8*)(As + aro[kq][1]);                    \
            short8 b0  = __builtin_bit_cast(short8, BC[kq][0]);                \
            short8 b1  = __builtin_bit_cast(short8, BC[kq][1]);                \
            acc[0][0] = __builtin_amdgcn_mfma_f32_16x16x32_bf16(               \
                af0, b0, acc[0][0], 0, 0, 0);                                  \
            acc[1][0] = __builtin_amdgcn_mfma_f32_16x16x32_bf16(               \
                af1, b0, acc[1][0], 0, 0, 0);                                  \
            acc[0][1] = __builtin_amdgcn_mfma_f32_16x16x32_bf16(               \
                af0, b1, acc[0][1], 0, 0, 0);                                  \
            acc[1][1] = __builtin_amdgcn_mfma_f32_16x16x32_bf16(               \
                af1, b1, acc[1][1], 0, 0, 0);                                  \
        }                                                                      \
    } while (0)

__global__ __launch_bounds__(512, 4) void gemm_max(const float* __restrict__ x,
                                                   const uint4* __restrict__ Bq,
                                                   const float* __restrict__ b1,
                                                   const float* __restrict__ b2,
                                                   unsigned* __restrict__ outu) {
    __shared__ __align__(16) char smem[32768];      // ring 16KB; epilogue 32KB

    const int t    = threadIdx.x;
    const int lane = t & 63;
    const int w    = t >> 6;                        // wave 0..7 -> cols w*32
    const int m0   = blockIdx.x * 32;

    // ---- A staging: thread t handles row=t>>4, k-chunk=t&15 (4 floats) ----
    const int rowS = t >> 4;
    const int kcS  = t & 15;
    const size_t aoff = row_base(m0 + rowS) + (size_t)(kcS * 4);
    const int    awb  = (rowS * 128 + kcS * 8) ^ ((rowS & 7) << 4);

    // ---- A fragment read offsets [kq][mf] (XOR-swizzled) ----
    int aro[2][2];
#pragma unroll
    for (int kq = 0; kq < 2; ++kq)
#pragma unroll
        for (int mf = 0; mf < 2; ++mf) {
            int row = mf * 16 + (lane & 15);
            aro[kq][mf] = (row * 128 + kq * 64 + (lane >> 4) * 16)
                          ^ ((row & 7) << 4);
        }

    const int bbase = w * 128 + lane;               // uint4 units

    // ---- prologue: stage tiles 0,1; prime pipelines ----
#pragma unroll
    for (int pt = 0; pt < 2; ++pt) {
        float4 v = *(const float4*)(x + aoff + pt * 64);
        *(uint2*)(smem + pt * 4096 + awb) = cvt4(v);
    }
    __syncthreads();

    float4 aA = *(const float4*)(x + aoff + 128);   // tile 2
    float4 aB = *(const float4*)(x + aoff + 192);   // tile 3
    uint4 BX[2][2], BY[2][2];
    LOAD_B(BX, 0);

    f32x4 acc[2][2];
#pragma unroll
    for (int mf = 0; mf < 2; ++mf)
#pragma unroll
        for (int nf = 0; nf < 2; ++nf) acc[mf][nf] = (f32x4){0.f, 0.f, 0.f, 0.f};

    // ---- main loop: 32 supersteps of 2 K-tiles, ONE barrier each ----
    for (int ks = 0; ks < 64; ks += 2) {
        // B for tile ks+1 (second half)
        LOAD_B(BY, ks + 1);
        // A for tile ks+4
        int ksl0 = (ks + 4 < 64) ? ks + 4 : 63;
        float4 aF0 = *(const float4*)(x + aoff + (size_t)(ksl0 * 64));
        // compute tile ks
        HALF(ks, BX);
        // stage tile ks+2 (data loaded 2 supersteps ago)
        *(uint2*)(smem + ((ks + 2) & 3) * 4096 + awb) = cvt4(aA);
        aA = aB; aB = aF0;
        // B for tile ks+2 (next superstep's first half)
        int ksb = (ks + 2 < 64) ? ks + 2 : 63;
        LOAD_B(BX, ksb);
        // A for tile ks+5
        int ksl1 = (ks + 5 < 64) ? ks + 5 : 63;
        float4 aF1 = *(const float4*)(x + aoff + (size_t)(ksl1 * 64));
        // compute tile ks+1
        HALF(ks + 1, BY);
        // stage tile ks+3
        *(uint2*)(smem + ((ks + 3) & 3) * 4096 + awb) = cvt4(aA);
        aA = aB; aB = aF1;
        // publish both staged tiles; readers of this superstep are drained
        asm volatile("s_waitcnt lgkmcnt(0)" ::: "memory");
        __builtin_amdgcn_s_barrier();
        asm volatile("" ::: "memory");
    }

    // ---- epilogue: spill acc to gt[32][256] f32 ----
    float* gt = (float*)smem;
#pragma unroll
    for (int mf = 0; mf < 2; ++mf)
#pragma unroll
        for (int nf = 0; nf < 2; ++nf) {
            int col = w * 32 + nf * 16 + (lane & 15);
#pragma unroll
            for (int q = 0; q < 4; ++q) {
                int row = mf * 16 + (lane >> 4) * 4 + q;
                gt[row * 256 + col] = acc[mf][nf][q];
            }
        }
    __syncthreads();

    // ---- gate + per-(b,c) running max + atomicMax ----
    if (t < 128) {
        const int   c   = t;
        const float bb1 = b1[c];
        const float bb2 = b2[c];
        int   bprev = (m0 < M_TOT ? m0 : M_TOT - 1) / P_CNT;
        float best  = -3.4e38f;
        for (int r = 0; r < 32; ++r) {
            int m = m0 + r;
            if (m > M_TOT - 1) m = M_TOT - 1;
            int bb = m / P_CNT;
            float c1 = gt[r * 256 + c] + bb1;
            float c2 = gt[r * 256 + 128 + c] + bb2;
            float g  = c1 / (1.f + __expf(-c2));
            if (bb != bprev) {
                atomicMax(&outu[bprev * 128 + c], ordenc(best));
                bprev = bb;
                best  = -3.4e38f;
            }
            best = fmaxf(best, g);
        }
        atomicMax(&outu[bprev * 128 + c], ordenc(best));
    }
}

// ---------------------------------------------------------------------------
// Kernel 3: decode order-encoded uints to floats in place.
// ---------------------------------------------------------------------------
__global__ __launch_bounds__(256) void unmap_out(unsigned* __restrict__ outu) {
    int i = blockIdx.x * 256 + threadIdx.x;
    if (i < 512) {
        unsigned u = outu[i];
        outu[i] = (u & 0x80000000u) ? (u ^ 0x80000000u) : ~u;
    }
}

extern "C" void kernel_launch(void* const* d_in, const int* in_sizes, int n_in,
                              void* d_out, int out_size, void* d_ws, size_t ws_size,
                              hipStream_t stream) {
    const float* x  = (const float*)d_in[0];
    const float* w1 = (const float*)d_in[1];
    const float* b1 = (const float*)d_in[2];
    const float* w2 = (const float*)d_in[3];
    const float* b2 = (const float*)d_in[4];

    uint4*    Bpf  = (uint4*)d_ws;                  // 2 MB fragment-major bf16
    unsigned* outu = (unsigned*)d_out;

    pack_w<<<dim3(512), dim3(256), 0, stream>>>(w1, w2, Bpf, outu);

    const int nblk = (M_TOT + 31) / 32;             // 493
    gemm_max<<<dim3(nblk), dim3(512), 0, stream>>>(x, (const uint4*)Bpf, b1, b2, outu);

    unmap_out<<<dim3(2), dim3(256), 0, stream>>>(outu);
}

// Round 9
// 70.909 us; speedup vs baseline: 1.2719x; 1.2719x over previous
//
#include <hip/hip_runtime.h>

// ---------------------------------------------------------------------------
// MalConvLowMem as GEMM: M=15748 windows (4096 contiguous floats), N=256
// (w1|w2), K=4096; epilogue g=(c1+b1)*sigmoid(c2+b2), max over positions.
// R9: BM=64, 16 waves (1024 thr), 1 block/CU, grid 248 (batch-aligned:
// 62 blocks x 64 rows per batch). B traffic halves vs BM=32 (496 MB L2).
// A in LDS ring-4 (8KB/slot), per-step lgkmcnt(0)+s_barrier (R7 schedule).
// B in regs, fragment-major with GATE-PAIR col permutation: wave w owns cols
// {w*8..w*8+7} u {128+w*8..135+w*8}; c1/c2 pairs are lanes l / l^8 ->
// epilogue fully in registers (shfl_xor 8/16/32 + 8 atomicMax per wave).
// ---------------------------------------------------------------------------

#define T_LEN 2000000
#define P_CNT 3937
#define M_TOT 15748
#define KD    4096

typedef __attribute__((ext_vector_type(8))) short short8;
typedef __attribute__((ext_vector_type(4))) float f32x4;

static __device__ __forceinline__ unsigned short f2bf(float f) {
    unsigned u = __builtin_bit_cast(unsigned, f);
    unsigned r = (u + 0x7FFFu + ((u >> 16) & 1u)) >> 16;   // RNE
    return (unsigned short)r;
}

static __device__ __forceinline__ unsigned ordenc(float f) {
    unsigned u = __builtin_bit_cast(unsigned, f);
    return (u & 0x80000000u) ? ~u : (u | 0x80000000u);
}

// (batch bb, position p<=3936) -> flat float offset of window start in x
static __device__ __forceinline__ size_t row_base_bp(int bb, int p) {
    int j, kp;
    if (p < 3875) { j = p / 125; kp = p - j * 125; }
    else          { j = 31;      kp = p - 3875; }
    long pos = (long)j * 63489 + (long)kp * 512;
    return ((size_t)bb * T_LEN + (size_t)pos) * 8u;
}

// 4 fp32 -> 4 bf16 (uint2) via v_cvt_pk_bf16_f32 (RNE)
static __device__ __forceinline__ uint2 cvt4(float4 v) {
    unsigned lo, hi;
    asm("v_cvt_pk_bf16_f32 %0, %1, %2" : "=v"(lo) : "v"(v.x), "v"(v.y));
    asm("v_cvt_pk_bf16_f32 %0, %1, %2" : "=v"(hi) : "v"(v.z), "v"(v.w));
    uint2 u; u.x = lo; u.y = hi;
    return u;
}

// ---------------------------------------------------------------------------
// Kernel 1: repack weights fragment-major WITH gate-pair col permutation:
// chunk c = ((ks*2+kq)*16 + w)*64 + l  (uint4) holds, for cl=l&15,
//   n = cl<8 ? w*8+cl : 128 + w*8 + (cl-8)
//   k = ks*64 + kq*32 + (l>>4)*8 + 0..7
//   W'[n][k] = (n<128 ? w1 : w2)[n&127][e=k&7][t=k>>3]  as bf16.
// Also init 512 output slots to order-encoded -inf.
// ---------------------------------------------------------------------------
__global__ __launch_bounds__(256) void pack_w(const float* __restrict__ w1,
                                              const float* __restrict__ w2,
                                              uint4* __restrict__ Bpf,
                                              unsigned* __restrict__ outu) {
    int c = blockIdx.x * 256 + threadIdx.x;         // grid 512 -> 131072
    if (c < 512) outu[c] = 0u;
    if (c >= 131072) return;
    int l  = c & 63;
    int w  = (c >> 6) & 15;                          // wave 0..15
    int kq = (c >> 10) & 1;
    int ks = c >> 11;
    int cl = l & 15;
    int n  = (cl < 8) ? (w * 8 + cl) : (128 + w * 8 + (cl - 8));
    int kb = ks * 64 + kq * 32 + ((l >> 4) << 3);
    const float* src = (n < 128) ? w1 : w2;
    int cc = n & 127;
    unsigned short h[8];
#pragma unroll
    for (int j = 0; j < 8; ++j) {
        int k = kb + j;
        h[j] = f2bf(src[cc * 4096 + (k & 7) * 512 + (k >> 3)]);
    }
    uint4 v;
    v.x = (unsigned)h[0] | ((unsigned)h[1] << 16);
    v.y = (unsigned)h[2] | ((unsigned)h[3] << 16);
    v.z = (unsigned)h[4] | ((unsigned)h[5] << 16);
    v.w = (unsigned)h[6] | ((unsigned)h[7] << 16);
    Bpf[c] = v;
}

// ---------------------------------------------------------------------------
// Kernel 2: GEMM + gate + max. 1024 thr / 16 waves, wave tile 64 rows x
// 16 cols (permuted), acc[4] f32x4. A ring-4 in LDS (4 x 8KB).
// ---------------------------------------------------------------------------
#define LOAD_B(BB, KS)                                                         \
    do {                                                                       \
        _Pragma("unroll")                                                      \
        for (int kq = 0; kq < 2; ++kq)                                         \
            BB[kq] = Bq[((KS) * 2 + kq) * 1024 + bbase];                       \
    } while (0)

#define STEP(KS, BCUR, BNXT)                                                   \
    do {                                                                       \
        const int ks_ = (KS);                                                  \
        const int ksn = (ks_ + 1 < 64) ? ks_ + 1 : 63;                         \
        LOAD_B(BNXT, ksn);                                                     \
        const int ksl = (ks_ + 4 < 64) ? ks_ + 4 : 63;                         \
        float4 aF = *(const float4*)(x + aoff + (size_t)(ksl * 64));           \
        const char* As = smem + (ks_ & 3) * 8192;                              \
        _Pragma("unroll")                                                      \
        for (int kq = 0; kq < 2; ++kq) {                                       \
            short8 b = __builtin_bit_cast(short8, BCUR[kq]);                   \
            _Pragma("unroll")                                                  \
            for (int mf = 0; mf < 4; ++mf) {                                   \
                short8 af = *(const short8*)(As + aro[kq][mf]);                \
                acc[mf] = __builtin_amdgcn_mfma_f32_16x16x32_bf16(             \
                    af, b, acc[mf], 0, 0, 0);                                  \
            }                                                                  \
        }                                                                      \
        *(uint2*)(smem + ((ks_ + 2) & 3) * 8192 + awb) = cvt4(aA);             \
        aA = aB; aB = aF;                                                      \
        asm volatile("s_waitcnt lgkmcnt(0)" ::: "memory");                     \
        __builtin_amdgcn_s_barrier();                                          \
        asm volatile("" ::: "memory");                                         \
    } while (0)

__global__ __launch_bounds__(1024, 4) void gemm_max(const float* __restrict__ x,
                                                    const uint4* __restrict__ Bq,
                                                    const float* __restrict__ b1,
                                                    const float* __restrict__ b2,
                                                    unsigned* __restrict__ outu) {
    __shared__ __align__(16) char smem[32768];      // ring-4 of 8KB

    const int t    = threadIdx.x;
    const int lane = t & 63;
    const int w    = t >> 6;                        // wave 0..15
    const int bid  = blockIdx.x;
    const int bb   = bid / 62;                      // batch (block-uniform)
    const int p0   = (bid % 62) * 64;               // first position of block

    // ---- A staging: thread t handles row=t>>4 (0..63), k-chunk t&15 ----
    const int rowS = t >> 4;
    const int kcS  = t & 15;
    int pS = p0 + rowS; if (pS > P_CNT - 1) pS = P_CNT - 1;
    const size_t aoff = row_base_bp(bb, pS) + (size_t)(kcS * 4);
    const int    awb  = (rowS * 128 + kcS * 8) ^ ((rowS & 7) << 4);

    // ---- A fragment read offsets [kq][mf] (XOR-swizzled) ----
    int aro[2][2 * 2];
#pragma unroll
    for (int kq = 0; kq < 2; ++kq)
#pragma unroll
        for (int mf = 0; mf < 4; ++mf) {
            int row = mf * 16 + (lane & 15);
            aro[kq][mf] = (row * 128 + kq * 64 + (lane >> 4) * 16)
                          ^ ((row & 7) << 4);
        }

    const int bbase = w * 64 + lane;                // uint4 units

    // ---- prologue: stage tiles 0,1; prime pipelines ----
#pragma unroll
    for (int pt = 0; pt < 2; ++pt) {
        float4 v = *(const float4*)(x + aoff + pt * 64);
        *(uint2*)(smem + pt * 8192 + awb) = cvt4(v);
    }
    __syncthreads();

    float4 aA = *(const float4*)(x + aoff + 128);   // tile 2
    float4 aB = *(const float4*)(x + aoff + 192);   // tile 3
    uint4 BX[2], BY[2];
    LOAD_B(BX, 0);

    f32x4 acc[4];
#pragma unroll
    for (int mf = 0; mf < 4; ++mf) acc[mf] = (f32x4){0.f, 0.f, 0.f, 0.f};

    for (int ks = 0; ks < 64; ks += 2) {
        STEP(ks, BX, BY);
        STEP(ks + 1, BY, BX);
    }

    // ---- epilogue: in-register gate + max (no LDS) ----
    // lane cl=lane&15: cl<8 -> col c1 = w*8+cl; partner c2 in lane^8.
    const int   cidx = w * 8 + (lane & 7);
    const float bb1  = b1[cidx];
    const float bb2  = b2[cidx];
    float best = -3.4e38f;
#pragma unroll
    for (int mf = 0; mf < 4; ++mf)
#pragma unroll
        for (int q = 0; q < 4; ++q) {
            float v  = acc[mf][q];
            float ov = __shfl_xor(v, 8);
            float c1 = v + bb1;
            float c2 = ov + bb2;
            float g  = c1 / (1.f + __expf(-c2));
            best = fmaxf(best, g);
        }
    // reduce over the 4 row-groups (lane bits 4,5); batch is block-uniform
    best = fmaxf(best, __shfl_xor(best, 16));
    best = fmaxf(best, __shfl_xor(best, 32));
    if (lane < 8)
        atomicMax(&outu[bb * 128 + w * 8 + lane], ordenc(best));
}

// ---------------------------------------------------------------------------
// Kernel 3: decode order-encoded uints to floats in place.
// ---------------------------------------------------------------------------
__global__ __launch_bounds__(256) void unmap_out(unsigned* __restrict__ outu) {
    int i = blockIdx.x * 256 + threadIdx.x;
    if (i < 512) {
        unsigned u = outu[i];
        outu[i] = (u & 0x80000000u) ? (u ^ 0x80000000u) : ~u;
    }
}

extern "C" void kernel_launch(void* const* d_in, const int* in_sizes, int n_in,
                              void* d_out, int out_size, void* d_ws, size_t ws_size,
                              hipStream_t stream) {
    const float* x  = (const float*)d_in[0];
    const float* w1 = (const float*)d_in[1];
    const float* b1 = (const float*)d_in[2];
    const float* w2 = (const float*)d_in[3];
    const float* b2 = (const float*)d_in[4];

    uint4*    Bpf  = (uint4*)d_ws;                  // 2 MB fragment-major bf16
    unsigned* outu = (unsigned*)d_out;

    pack_w<<<dim3(512), dim3(256), 0, stream>>>(w1, w2, Bpf, outu);

    const int nblk = 62 * 4;                        // 248, batch-aligned
    gemm_max<<<dim3(nblk), dim3(1024), 0, stream>>>(x, (const uint4*)Bpf, b1, b2, outu);

    unmap_out<<<dim3(2), dim3(256), 0, stream>>>(outu);
}